// Round 17
// baseline (687.269 us; speedup 1.0000x reference)
//
#include <hip/hip_runtime.h>
#include <stdint.h>

#define DEV static __device__ __forceinline__

typedef __bf16 bf16x8 __attribute__((ext_vector_type(8)));
typedef float f32x4 __attribute__((ext_vector_type(4)));

constexpr int Bc = 2, Sc = 4096, Dc = 2048, Hc = 16, KVHc = 8, HDc = 128;
constexpr int DQKc = 1024, DVc = 2048;
constexpr int Mc = Bc * Sc;       // 8192 rows
constexpr int NCATc = 6144;       // Q(1024) | K(1024) | V(2048) | Graw(2048)
constexpr int CT = 64;            // scan chunk length
constexpr int NCH = Sc / CT;      // 64 chunks per sequence
constexpr int COEF_STRIDE = 25088; // bytes: M2 8KB | F 16KB | gA/gB 512B
constexpr float EPSc = 1e-6f;

DEV uint16_t f2bf(float f) {
  uint32_t u = __float_as_uint(f);
  u += 0x7FFFu + ((u >> 16) & 1u);   // RNE
  return (uint16_t)(u >> 16);
}
DEV float bf2f(uint16_t h) { return __uint_as_float(((uint32_t)h) << 16); }
DEV float sigmoidf_(float z) { return 1.0f / (1.0f + __expf(-z)); }

DEV void unpack8(uint4 u, float* f) {
  f[0] = __uint_as_float(u.x << 16); f[1] = __uint_as_float(u.x & 0xFFFF0000u);
  f[2] = __uint_as_float(u.y << 16); f[3] = __uint_as_float(u.y & 0xFFFF0000u);
  f[4] = __uint_as_float(u.z << 16); f[5] = __uint_as_float(u.z & 0xFFFF0000u);
  f[6] = __uint_as_float(u.w << 16); f[7] = __uint_as_float(u.w & 0xFFFF0000u);
}

DEV void gload16(void* lds, const void* g) {
  auto gp = (const __attribute__((address_space(1))) uint32_t*)(uintptr_t)g;
  auto lp = (__attribute__((address_space(3))) uint32_t*)(uint32_t)(uintptr_t)lds;
  __builtin_amdgcn_global_load_lds(gp, lp, 16, 0, 0);
}

// LDS-only barrier: make ds ops visible without draining vmcnt.
DEV void sync_lds() {
  asm volatile("s_waitcnt lgkmcnt(0)" ::: "memory");
  __builtin_amdgcn_sched_barrier(0);
  __builtin_amdgcn_s_barrier();
  __builtin_amdgcn_sched_barrier(0);
}

// m201-style pre-MFMA sync: barrier (wave rhythm), then wait own ds_reads,
// then pin the schedule so MFMAs aren't hoisted above (rule #18).
DEV void mfma_gate() {
  __builtin_amdgcn_s_barrier();
  asm volatile("s_waitcnt lgkmcnt(0)" ::: "memory");
  __builtin_amdgcn_sched_barrier(0);
}

// ---------------- fused f32 -> bf16 cast over 6 ranges ----------------
__global__ __launch_bounds__(256) void cast6_kernel(const float* __restrict__ x,
                                                    const float* __restrict__ wq,
                                                    const float* __restrict__ wk,
                                                    const float* __restrict__ wv,
                                                    const float* __restrict__ gw,
                                                    const float* __restrict__ wo,
                                                    uint16_t* __restrict__ xb,
                                                    uint16_t* __restrict__ wcat,
                                                    uint16_t* __restrict__ wob) {
  int i = blockIdx.x * blockDim.x + threadIdx.x;
  const int stride = gridDim.x * blockDim.x;
  for (; i < 8388608; i += stride) {
    const float* src;
    uint16_t* dst;
    int off;
    if (i < 4194304)      { src = x;  dst = xb;                     off = i; }
    else if (i < 4718592) { src = wq; dst = wcat;                   off = i - 4194304; }
    else if (i < 5242880) { src = wk; dst = wcat + DQKc * Dc;       off = i - 4718592; }
    else if (i < 6291456) { src = wv; dst = wcat + 2 * DQKc * Dc;   off = i - 5242880; }
    else if (i < 7340032) { src = gw; dst = wcat + 2 * DQKc * Dc + DVc * Dc; off = i - 6291456; }
    else                  { src = wo; dst = wob;                    off = i - 7340032; }
    float4 v = *(const float4*)(src + (size_t)off * 4);
    ushort4 o;
    o.x = f2bf(v.x); o.y = f2bf(v.y); o.z = f2bf(v.z); o.w = f2bf(v.w);
    *(ushort4*)(dst + (size_t)off * 4) = o;
  }
}

// ---------------- 256x256 8-phase bf16 GEMM, C = A @ B^T ----------------
// Column-major XCD mapping (requires Ndim/256 % 8 == 0). m201-style phases:
// {ds_read + stage-issue -> barrier -> lgkmcnt(0) -> setprio+MFMA -> barrier}.
template <typename OutT>
__global__ __launch_bounds__(512, 2) void gemm256_bt(const uint16_t* __restrict__ A,
                                                     const uint16_t* __restrict__ Bw,
                                                     OutT* __restrict__ C, int Ndim, int Kdim,
                                                     int lda) {
  __shared__ uint16_t sT[2][2][2][8192];   // [buf][mat A/B][khalf][256 rows * 32 cols]

  const int nbn = Ndim / 256;
  const int cpx = nbn >> 3;                 // bn columns per XCD
  const int xcd = blockIdx.x & 7, lin = blockIdx.x >> 3;
  const int bn = xcd * cpx + lin % cpx;
  const int bm = lin / cpx;

  const int tid = threadIdx.x;
  const int wid = tid >> 6, lane = tid & 63;
  const int wm = wid >> 2, wn = wid & 3;
  const int lr = lane & 15;
  const int sswz8 = (((lane >> 4) ^ ((lr >> 1) & 3)) * 8);
  const int arow_base = wm * 128 + lr;
  const int brow_base = wn * 64 + lr;

  const uint16_t* Ab = A + (size_t)(bm * 256) * lda;
  const uint16_t* Bb = Bw + (size_t)(bn * 256) * Kdim;
  const int NT = Kdim >> 6;

  int srowA[2];
  int soff[2];
  const int wbase = tid & ~63;
#pragma unroll
  for (int u = 0; u < 2; ++u) {
    int L = u * 512 + tid;
    srowA[u] = L >> 2;
    soff[u] = (((L & 3) ^ ((L >> 3) & 3)) * 8);
  }

  auto STAGE = [&](int buf, int mat, int kh, int kt) {
    const uint16_t* gb = mat == 0 ? Ab : Bb;
    const int ld = mat == 0 ? lda : Kdim;
    uint16_t* rg = &sT[buf][mat][kh][0];
#pragma unroll
    for (int u = 0; u < 2; ++u) {
      const uint16_t* g = gb + (size_t)srowA[u] * ld + kt * 64 + kh * 32 + soff[u];
      gload16(rg + (u * 512 + wbase) * 8, g);
    }
  };

  f32x4 acc[8][4] = {};
  bf16x8 bfr[4];

  STAGE(0, 0, 0, 0); STAGE(0, 1, 0, 0);
  STAGE(0, 0, 1, 0); STAGE(0, 1, 1, 0);
  STAGE(1, 0, 0, 1); STAGE(1, 1, 0, 1);
  asm volatile("s_waitcnt vmcnt(4)" ::: "memory");
  __builtin_amdgcn_s_barrier();

  for (int kt = 0; kt < NT; ++kt) {
    const int buf = kt & 1;
    const uint16_t* aR0 = &sT[buf][0][0][0];
    const uint16_t* bR0 = &sT[buf][1][0][0];
    const uint16_t* aR1 = &sT[buf][0][1][0];
    const uint16_t* bR1 = &sT[buf][1][1][0];

    // ---- P1: k-half 0, m-frags 0..3 (+ all 4 b-frags kh0) ----
    {
      bf16x8 af[4];
#pragma unroll
      for (int m = 0; m < 4; ++m)
        af[m] = *(const bf16x8*)&aR0[(arow_base + m * 16) * 32 + sswz8];
#pragma unroll
      for (int n = 0; n < 4; ++n)
        bfr[n] = *(const bf16x8*)&bR0[(brow_base + n * 16) * 32 + sswz8];
      if (kt + 1 < NT) STAGE(buf ^ 1, 0, 1, kt + 1);
      mfma_gate();
      __builtin_amdgcn_s_setprio(1);
#pragma unroll
      for (int m = 0; m < 4; ++m)
#pragma unroll
        for (int n = 0; n < 4; ++n)
          acc[m][n] = __builtin_amdgcn_mfma_f32_16x16x32_bf16(af[m], bfr[n], acc[m][n], 0, 0, 0);
      __builtin_amdgcn_s_setprio(0);
      __builtin_amdgcn_s_barrier();
    }
    // ---- P2: k-half 0, m-frags 4..7 (b reused) ----
    {
      bf16x8 af[4];
#pragma unroll
      for (int m = 0; m < 4; ++m)
        af[m] = *(const bf16x8*)&aR0[(arow_base + (m + 4) * 16) * 32 + sswz8];
      if (kt + 1 < NT) STAGE(buf ^ 1, 1, 1, kt + 1);
      mfma_gate();
      __builtin_amdgcn_s_setprio(1);
#pragma unroll
      for (int m = 0; m < 4; ++m)
#pragma unroll
        for (int n = 0; n < 4; ++n)
          acc[m + 4][n] = __builtin_amdgcn_mfma_f32_16x16x32_bf16(af[m], bfr[n], acc[m + 4][n], 0, 0, 0);
      __builtin_amdgcn_s_setprio(0);
      __builtin_amdgcn_s_barrier();
    }
    // ---- P3: k-half 1, m-frags 0..3 (+ all 4 b-frags kh1) ----
    {
      bf16x8 af[4];
#pragma unroll
      for (int m = 0; m < 4; ++m)
        af[m] = *(const bf16x8*)&aR1[(arow_base + m * 16) * 32 + sswz8];
#pragma unroll
      for (int n = 0; n < 4; ++n)
        bfr[n] = *(const bf16x8*)&bR1[(brow_base + n * 16) * 32 + sswz8];
      if (kt + 2 < NT) STAGE(buf, 0, 0, kt + 2);
      mfma_gate();
      __builtin_amdgcn_s_setprio(1);
#pragma unroll
      for (int m = 0; m < 4; ++m)
#pragma unroll
        for (int n = 0; n < 4; ++n)
          acc[m][n] = __builtin_amdgcn_mfma_f32_16x16x32_bf16(af[m], bfr[n], acc[m][n], 0, 0, 0);
      __builtin_amdgcn_s_setprio(0);
      __builtin_amdgcn_s_barrier();
    }
    // ---- P4: k-half 1, m-frags 4..7 ----
    {
      bf16x8 af[4];
#pragma unroll
      for (int m = 0; m < 4; ++m)
        af[m] = *(const bf16x8*)&aR1[(arow_base + (m + 4) * 16) * 32 + sswz8];
      if (kt + 2 < NT) STAGE(buf, 1, 0, kt + 2);
      mfma_gate();
      __builtin_amdgcn_s_setprio(1);
#pragma unroll
      for (int m = 0; m < 4; ++m)
#pragma unroll
        for (int n = 0; n < 4; ++n)
          acc[m + 4][n] = __builtin_amdgcn_mfma_f32_16x16x32_bf16(af[m], bfr[n], acc[m + 4][n], 0, 0, 0);
      __builtin_amdgcn_s_setprio(0);
    }
    // ---- K-tile boundary: counted vmcnt (never 0 mid-loop), then barrier ----
    if (kt + 1 < NT) {
      if (kt + 2 < NT)
        asm volatile("s_waitcnt vmcnt(4)" ::: "memory");
      else
        asm volatile("s_waitcnt vmcnt(0)" ::: "memory");
      __builtin_amdgcn_s_barrier();
    }
  }

  const int r0 = (lane >> 4) * 4;
#pragma unroll
  for (int m = 0; m < 8; ++m)
#pragma unroll
    for (int n = 0; n < 4; ++n) {
      int col = bn * 256 + wn * 64 + n * 16 + lr;
#pragma unroll
      for (int j = 0; j < 4; ++j) {
        int row = bm * 256 + wm * 128 + m * 16 + r0 + j;
        float val = acc[m][n][j];
        if constexpr (sizeof(OutT) == 2)
          C[(size_t)row * Ndim + col] = (OutT)f2bf(val);
        else
          C[(size_t)row * Ndim + col] = (OutT)val;
      }
    }
}

// ---------------- alpha/beta (fp32, sigmoid fused, 4 rows/block, 8-way K-split) ----------------
__global__ __launch_bounds__(256) void alphabeta_kernel(const float* __restrict__ x,
                                                        const float* __restrict__ aw,
                                                        const float* __restrict__ abias,
                                                        const float* __restrict__ bw,
                                                        const float* __restrict__ bbias,
                                                        float* __restrict__ out) {
  __shared__ float xs[4 * Dc];   // 32 KB
  const int row0 = blockIdx.x * 4;
  const float* xp = x + (size_t)row0 * Dc;
  for (int i = threadIdx.x; i < 4 * Dc / 4; i += 256)
    *(float4*)&xs[i * 4] = *(const float4*)(xp + (size_t)i * 4);
  __syncthreads();
  const int o = threadIdx.x >> 3, lg = threadIdx.x & 7;
  const float* wrow = (o < 16) ? (aw + (size_t)o * Dc) : (bw + (size_t)(o - 16) * Dc);
  float s0 = 0.f, s1 = 0.f, s2 = 0.f, s3 = 0.f;
  for (int k = lg * 4; k < Dc; k += 32) {
    float4 wv = *(const float4*)(wrow + k);
    float4 x0 = *(const float4*)&xs[k];
    float4 x1 = *(const float4*)&xs[Dc + k];
    float4 x2 = *(const float4*)&xs[2 * Dc + k];
    float4 x3 = *(const float4*)&xs[3 * Dc + k];
    s0 += x0.x * wv.x + x0.y * wv.y + x0.z * wv.z + x0.w * wv.w;
    s1 += x1.x * wv.x + x1.y * wv.y + x1.z * wv.z + x1.w * wv.w;
    s2 += x2.x * wv.x + x2.y * wv.y + x2.z * wv.z + x2.w * wv.w;
    s3 += x3.x * wv.x + x3.y * wv.y + x3.z * wv.z + x3.w * wv.w;
  }
#pragma unroll
  for (int m = 1; m < 8; m <<= 1) {
    s0 += __shfl_xor(s0, m); s1 += __shfl_xor(s1, m);
    s2 += __shfl_xor(s2, m); s3 += __shfl_xor(s3, m);
  }
  if (lg == 0) {
    float bias = (o < 16) ? abias[o] : bbias[o - 16];
    float scale = (o >= 16) ? 0.08838834764831845f : 1.0f;   // 1/sqrt(128)
    out[(size_t)(row0 + 0) * 32 + o] = sigmoidf_(s0 + bias) * scale;
    out[(size_t)(row0 + 1) * 32 + o] = sigmoidf_(s1 + bias) * scale;
    out[(size_t)(row0 + 2) * 32 + o] = sigmoidf_(s2 + bias) * scale;
    out[(size_t)(row0 + 3) * 32 + o] = sigmoidf_(s3 + bias) * scale;
  }
}

// ---------------- per-chunk coefficient precompute (T=64, GQA-deduped, +F) ----------------
// FUSES causal conv(k=4) + head RMSNorm: reads RAW C1 Q/K sections, computes
// normed bf16 K/Q into LDS (MFMA) AND global Qn/Kn (scan) — single rounding.
__global__ __launch_bounds__(256) void scores_kernel(const uint16_t* __restrict__ C1,
                                                     const float* __restrict__ qcw,
                                                     const float* __restrict__ kcw,
                                                     const float* __restrict__ nqw,
                                                     const float* __restrict__ nkw,
                                                     const float* __restrict__ ab,
                                                     uint8_t* __restrict__ coef,
                                                     uint16_t* __restrict__ Qn,
                                                     uint16_t* __restrict__ Kn) {
  __shared__ __align__(16) char smem[137728];
  uint16_t* sK = (uint16_t*)smem;                  // [64][136]
  uint16_t* sQ = (uint16_t*)(smem + 17408);        // [64][136]
  uint16_t* sF = (uint16_t*)smem;                  // alias after solve: [128][72]
  uint16_t* sM2 = (uint16_t*)(smem + 18432);       // alias after solve: [64][72]
  float* Lb = (float*)(smem + 108544);             // [2][64]
  float* bbv = Lb + 128;                           // [2][64]
  uint16_t* Ktg = (uint16_t*)(smem + 109568);      // [128][72] K^T (swizzled cols)
  uint16_t* Et = (uint16_t*)(smem + 128000);       // [64][72] E^T bf16 (per-head)
  float* gCb = (float*)(smem + 137216);            // [2][64]

  auto Wt_p  = [&](int hd) { return (float*)(smem + hd * 17408); };
  auto Msh_p = [&](int hd) { return (uint16_t*)(smem + 34816 + hd * 18432); };
  auto Msl_p = [&](int hd) { return (uint16_t*)(smem + 44032 + hd * 18432); };
  auto Thh_p = [&](int hd) { return (uint16_t*)(smem + 71680 + hd * 18432); };
  auto Thl_p = [&](int hd) { return (uint16_t*)(smem + 80896 + hd * 18432); };

  const int bid = blockIdx.x;
  const int c = bid & 63, kh = (bid >> 6) & 7, b = bid >> 9;
  const int t0 = c * 64;
  const int tid = threadIdx.x;
  const int w = tid >> 6, l = tid & 63, lr = l & 15, lk = (l >> 4) * 8;
  const int sr = tid >> 2, sq2 = tid & 3;

  auto cb_p = [&](int hd) {
    return coef + (size_t)((b * Hc + kh * 2 + hd) * NCH + c) * COEF_STRIDE;
  };

  {  // fused conv(k=4)+RMSNorm staging
    const int ch0 = sq2 * 32;
    const int t = t0 + sr;
    float qa[32], ka[32];
    float sqs = 0.f, sks = 0.f;
#pragma unroll
    for (int u = 0; u < 4; ++u) {
      uint4 qt[4], kt4[4];
#pragma unroll
      for (int j = 0; j < 4; ++j) {
        int tt = t - 3 + j;
        if (tt >= 0) {
          size_t rbj = (size_t)(b * Sc + tt) * NCATc + kh * HDc + ch0 + u * 8;
          qt[j] = *(const uint4*)(C1 + rbj);
          kt4[j] = *(const uint4*)(C1 + rbj + 1024);
        } else {
          qt[j] = make_uint4(0, 0, 0, 0);
          kt4[j] = make_uint4(0, 0, 0, 0);
        }
      }
      float qf[4][8], kf[4][8];
#pragma unroll
      for (int j = 0; j < 4; ++j) { unpack8(qt[j], qf[j]); unpack8(kt4[j], kf[j]); }
#pragma unroll
      for (int e = 0; e < 8; ++e) {
        const int ch = kh * HDc + ch0 + u * 8 + e;
        float4 wq4 = *(const float4*)(qcw + ch * 4);
        float4 wk4 = *(const float4*)(kcw + ch * 4);
        float qv = qf[0][e] * wq4.x + qf[1][e] * wq4.y + qf[2][e] * wq4.z + qf[3][e] * wq4.w;
        float kv = kf[0][e] * wk4.x + kf[1][e] * wk4.y + kf[2][e] * wk4.z + kf[3][e] * wk4.w;
        qa[u * 8 + e] = qv; ka[u * 8 + e] = kv;
        sqs += qv * qv; sks += kv * kv;
      }
    }
    sqs += __shfl_xor(sqs, 1); sqs += __shfl_xor(sqs, 2);
    sks += __shfl_xor(sks, 1); sks += __shfl_xor(sks, 2);
    const float rq = rsqrtf(sqs * (1.f / HDc) + EPSc);
    const float rk = rsqrtf(sks * (1.f / HDc) + EPSc);
    const size_t gq = (size_t)(b * Sc + t) * DQKc + kh * HDc + ch0;
#pragma unroll
    for (int u = 0; u < 4; ++u) {
      uint32_t qpk[4], kpk[4];
#pragma unroll
      for (int p = 0; p < 4; ++p) {
        const int e = u * 8 + p * 2;
        const int cc = ch0 + e;
        uint16_t q0 = f2bf(nqw[cc] * qa[e] * rq);
        uint16_t q1 = f2bf(nqw[cc + 1] * qa[e + 1] * rq);
        uint16_t k0 = f2bf(nkw[cc] * ka[e] * rk);
        uint16_t k1 = f2bf(nkw[cc + 1] * ka[e + 1] * rk);
        qpk[p] = (uint32_t)q0 | ((uint32_t)q1 << 16);
        kpk[p] = (uint32_t)k0 | ((uint32_t)k1 << 16);
      }
      uint4 qv4 = make_uint4(qpk[0], qpk[1], qpk[2], qpk[3]);
      uint4 kv4 = make_uint4(kpk[0], kpk[1], kpk[2], kpk[3]);
      *(uint4*)&sQ[sr * 136 + ch0 + u * 8] = qv4;
      *(uint4*)&sK[sr * 136 + ch0 + u * 8] = kv4;
      *(uint4*)(Qn + gq + u * 8) = qv4;
      *(uint4*)(Kn + gq + u * 8) = kv4;
    }
  }
  if (tid < 128) {  // log-space decays
    const int hd = tid >> 6, tt = tid & 63;
    const float* abp = ab + (size_t)(b * Sc + t0 + tt) * 32 + (kh * 2 + hd);
    float av = fmaxf(abp[0], 1e-30f);
    float bv = abp[16];
    float la = log2f(av);
    float L = la;
#pragma unroll
    for (int off = 1; off < 64; off <<= 1) {
      float up = __shfl_up(L, off, 64);
      if (tt >= off) L += up;
    }
    Lb[hd * 64 + tt] = L; bbv[hd * 64 + tt] = bv;
    float* gout = (float*)(cb_p(hd) + 24576);
    gout[tt] = exp2f(L - la);   // gA = G_{i-1}
    gout[64 + tt] = exp2f(L);   // gB = G_i
  }
  __syncthreads();

  // KK = K K^T, QK = Q K^T
  f32x4 kkacc[4] = {}, qkacc[4] = {};
#pragma unroll
  for (int k0 = 0; k0 < 128; k0 += 32) {
    bf16x8 ka = *(const bf16x8*)&sK[(16 * w + lr) * 136 + k0 + lk];
    bf16x8 qa = *(const bf16x8*)&sQ[(16 * w + lr) * 136 + k0 + lk];
#pragma unroll
    for (int n = 0; n < 4; ++n) {
      bf16x8 kb = *(const bf16x8*)&sK[(16 * n + lr) * 136 + k0 + lk];
      kkacc[n] = __builtin_amdgcn_mfma_f32_16x16x32_bf16(ka, kb, kkacc[n], 0, 0, 0);
      qkacc[n] = __builtin_amdgcn_mfma_f32_16x16x32_bf16(qa, kb, qkacc[n], 0, 0, 0);
    }
  }
  __syncthreads();

  // K^T scatter (sq2-keyed col swizzle) + per-head gC, while sK still valid
  {
#pragma unroll
    for (int u = 0; u < 4; ++u) {
      uint4 kd = *(const uint4*)&sK[sr * 136 + sq2 * 32 + u * 8];
      const int c0 = sq2 * 32 + u * 8;
      const int tsw = sr ^ (sq2 << 4);
      uint32_t x0 = kd.x, x1 = kd.y, x2 = kd.z, x3 = kd.w;
      Ktg[(c0 + 0) * 72 + tsw] = (uint16_t)x0; Ktg[(c0 + 1) * 72 + tsw] = (uint16_t)(x0 >> 16);
      Ktg[(c0 + 2) * 72 + tsw] = (uint16_t)x1; Ktg[(c0 + 3) * 72 + tsw] = (uint16_t)(x1 >> 16);
      Ktg[(c0 + 4) * 72 + tsw] = (uint16_t)x2; Ktg[(c0 + 5) * 72 + tsw] = (uint16_t)(x2 >> 16);
      Ktg[(c0 + 6) * 72 + tsw] = (uint16_t)x3; Ktg[(c0 + 7) * 72 + tsw] = (uint16_t)(x3 >> 16);
    }
    if (tid < 128) {
      const int hd = tid >> 6, tt = tid & 63;
      gCb[hd * 64 + tt] = exp2f(Lb[hd * 64 + 63] - Lb[hd * 64 + tt]) * bbv[hd * 64 + tt];
    }
  }
  __syncthreads();

  // fold per head (overwrites sK/sQ with Wt0/Wt1)
#pragma unroll
  for (int hd = 0; hd < 2; ++hd) {
    float* Wt = Wt_p(hd);
    uint16_t* Mh = Msh_p(hd);
    uint16_t* Ml = Msl_p(hd);
    const float* Lh = Lb + hd * 64;
    const float* bh = bbv + hd * 64;
#pragma unroll
    for (int n = 0; n < 4; ++n)
#pragma unroll
      for (int jj = 0; jj < 4; ++jj) {
        const int i = 16 * w + (l >> 4) * 4 + jj;
        const int j = 16 * n + lr;
        float Li = Lh[i];
        float Lim = (i > 0) ? Lh[(i > 0) ? i - 1 : 0] : 0.f;
        float Lj = Lh[j];
        float bj = bh[j];
        float wv = (j < i) ? exp2f(Lim - Lj) * bj * kkacc[n][jj] : 0.f;
        Wt[j * 68 + i] = wv;                       // W^T
        float ms = (j <= i) ? exp2f(Li - Lj) * bj * qkacc[n][jj] : 0.f;
        uint16_t mh = f2bf(ms);
        Mh[i * 72 + j] = mh;
        Ml[i * 72 + j] = f2bf(ms - bf2f(mh));
      }
  }
  __syncthreads();

  // Tinv = (I + tril(W,-1))^-1 forward substitution; wave hd solves head hd.
  if (tid < 128) {
    const int hd = tid >> 6, col = tid & 63;
    float* Wt = Wt_p(hd);
    uint16_t* Th = Thh_p(hd);
    uint16_t* Tl = Thl_p(hd);
    float acc[64];
#pragma unroll
    for (int i = 0; i < 64; ++i) acc[i] = 0.f;
#pragma unroll
    for (int ll = 0; ll < 64; ++ll) {
      float xl = ((col == ll) ? 1.f : 0.f) - acc[ll];
      uint16_t xh = f2bf(xl);
      Th[col * 72 + ll] = xh;                      // transposed: [col j][row l]
      Tl[col * 72 + ll] = f2bf(xl - bf2f(xh));
#pragma unroll
      for (int i = ll + 1; i < 64; ++i)
        acc[i] = fmaf(Wt[ll * 68 + i], xl, acc[i]);
    }
  }
  __syncthreads();

  for (int hd = 0; hd < 2; ++hd) {
    uint16_t* Mh = Msh_p(hd);
    uint16_t* Ml = Msl_p(hd);
    uint16_t* Th = Thh_p(hd);
    uint16_t* Tl = Thl_p(hd);
    uint16_t* m2out = (uint16_t*)cb_p(hd);
    uint16_t* fout = (uint16_t*)cb_p(hd) + 4096;

    // a) Et^T[j][t] = gC[t]*(Thh+Thl)[j][t]
    {
      const int j2 = tid >> 2, tq = tid & 3;
#pragma unroll
      for (int p = 0; p < 16; ++p) {
        int t1 = tq * 16 + p;
        float ev = gCb[hd * 64 + t1] * (bf2f(Th[j2 * 72 + t1]) + bf2f(Tl[j2 * 72 + t1]));
        Et[j2 * 72 + t1] = f2bf(ev);
      }
    }
    __syncthreads();

    // b) M2 = M_s * Tinv (hi/lo MFMA); F = K^T * E (MFMA)
    f32x4 m2acc[4] = {};
#pragma unroll
    for (int k0 = 0; k0 < 64; k0 += 32) {
      bf16x8 ah = *(const bf16x8*)&Mh[(16 * w + lr) * 72 + k0 + lk];
      bf16x8 al = *(const bf16x8*)&Ml[(16 * w + lr) * 72 + k0 + lk];
#pragma unroll
      for (int n = 0; n < 4; ++n) {
        bf16x8 bhf = *(const bf16x8*)&Th[(16 * n + lr) * 72 + k0 + lk];
        bf16x8 blf = *(const bf16x8*)&Tl[(16 * n + lr) * 72 + k0 + lk];
        m2acc[n] = __builtin_amdgcn_mfma_f32_16x16x32_bf16(ah, bhf, m2acc[n], 0, 0, 0);
        m2acc[n] = __builtin_amdgcn_mfma_f32_16x16x32_bf16(ah, blf, m2acc[n], 0, 0, 0);
        m2acc[n] = __builtin_amdgcn_mfma_f32_16x16x32_bf16(al, bhf, m2acc[n], 0, 0, 0);
      }
    }
    f32x4 facc[2][4] = {};
#pragma unroll
    for (int k0 = 0; k0 < 64; k0 += 32) {
      bf16x8 eb[4];
#pragma unroll
      for (int n = 0; n < 4; ++n)
        eb[n] = *(const bf16x8*)&Et[(16 * n + lr) * 72 + k0 + lk];
      const int ksw = (k0 + lk) ^ (w << 4);
      bf16x8 ka0 = *(const bf16x8*)&Ktg[(32 * w + lr) * 72 + ksw];
      bf16x8 ka1 = *(const bf16x8*)&Ktg[(32 * w + 16 + lr) * 72 + ksw];
#pragma unroll
      for (int n = 0; n < 4; ++n) {
        facc[0][n] = __builtin_amdgcn_mfma_f32_16x16x32_bf16(ka0, eb[n], facc[0][n], 0, 0, 0);
        facc[1][n] = __builtin_amdgcn_mfma_f32_16x16x32_bf16(ka1, eb[n], facc[1][n], 0, 0, 0);
      }
    }
#pragma unroll
    for (int n = 0; n < 4; ++n)
#pragma unroll
      for (int jj = 0; jj < 4; ++jj) {
        const int i = 16 * w + (l >> 4) * 4 + jj;
        const int j = 16 * n + lr;
        sM2[i * 72 + j] = f2bf(m2acc[n][jj]);
        sF[(32 * w + (l >> 4) * 4 + jj) * 72 + j] = f2bf(facc[0][n][jj]);
        sF[(32 * w + 16 + (l >> 4) * 4 + jj) * 72 + j] = f2bf(facc[1][n][jj]);
      }
    __syncthreads();
    // c) packed copies out, slot-permuted: logical slot s of row r -> s ^ (r&7)
    {
      const int i2 = tid >> 2, tq = tid & 3;
      uint4 a0 = *(const uint4*)&sM2[i2 * 72 + tq * 16];
      uint4 a1 = *(const uint4*)&sM2[i2 * 72 + tq * 16 + 8];
      *(uint4*)(m2out + i2 * 64 + ((2 * tq) ^ (i2 & 7)) * 8) = a0;
      *(uint4*)(m2out + i2 * 64 + ((2 * tq + 1) ^ (i2 & 7)) * 8) = a1;
#pragma unroll
      for (int e = 0; e < 4; ++e) {
        int L = tid * 4 + e;
        int rw = L >> 3, s = L & 7;
        *(uint4*)(fout + rw * 64 + (s ^ (rw & 7)) * 8) = *(const uint4*)&sF[rw * 72 + s * 8];
      }
    }
    __syncthreads();   // protect sM2/sF/Et before next head
  }
}

// ---------------- MFMA chunked gated delta-rule scan (T=64, 2-phase) ----------------
__global__ __launch_bounds__(256, 1) void scan_kernel(const uint16_t* __restrict__ Qn,
                                                      const uint16_t* __restrict__ Kn,
                                                      uint16_t* C1,
                                                      const uint8_t* __restrict__ coef) {
  __shared__ __align__(16) uint16_t Kb[64 * 136];
  __shared__ __align__(16) uint16_t Qb[64 * 136];
  __shared__ __align__(16) uint16_t M2b[2][64 * 64];   // linear, slot-permuted
  __shared__ __align__(16) uint16_t Fb[2][128 * 64];   // linear, slot-permuted
  __shared__ __align__(16) uint16_t Vb[64 * 24];
  __shared__ __align__(16) uint16_t Rt[16 * 72];     // R^T [v][t]
  __shared__ __align__(16) uint16_t Sh[16 * 136];    // S^T hi [v][dk]
  __shared__ __align__(16) uint16_t Slo[16 * 136];   // S^T lo [v][dk]
  __shared__ float gABb[128];                        // gA[64] | gB[64]

  const int bid = blockIdx.x;
  const int kh = bid & 7;
  const int j2 = bid >> 3;
  const int sl = j2 >> 2;
  const int b = (j2 >> 1) & 1;
  const int h = kh * 2 + (j2 & 1);
  const int ch0 = (b * Hc + h) * NCH;

  const int tid = threadIdx.x;
  const int w = tid >> 6, l = tid & 63;
  const int lr = l & 15, lk = (l >> 4) * 8;
  const int row0 = 16 * w + (l >> 4) * 4;
  const int vcol = lr;
  const int sr = tid >> 2, sq2 = tid & 3;
  const int wbase = tid & ~63;

  const size_t kqbase = (size_t)(b * Sc) * DQKc + kh * HDc;
  const size_t vbase = (size_t)(b * Sc) * NCATc + 2048 + h * HDc + sl * 16;
  uint16_t* Gb = C1 + (size_t)(b * Sc) * NCATc + 4096 + h * HDc + sl * 16 + vcol;

  float sreg[2][4] = {};
  uint4 kA[4], kB[4], qA[4], qB[4];
  ushort4 gv0, gv1;

  auto LOADS = [&](int cn, int nb, uint4 (&kd)[4], uint4 (&qd)[4],
                   uint4& vd, float& gd, ushort4& gvd) {
    const uint16_t* cf = (const uint16_t*)(coef + (size_t)(ch0 + cn) * COEF_STRIDE);
#pragma unroll
    for (int u = 0; u < 2; ++u)
      gload16(&M2b[nb][(u * 256 + wbase) * 8], cf + (size_t)(u * 256 + tid) * 8);
#pragma unroll
    for (int u = 0; u < 4; ++u)
      gload16(&Fb[nb][(u * 256 + wbase) * 8], cf + 4096 + (size_t)(u * 256 + tid) * 8);
    const size_t rb = kqbase + (size_t)(cn * CT + sr) * DQKc + sq2 * 32;
#pragma unroll
    for (int u = 0; u < 4; ++u) {
      kd[u] = *(const uint4*)(Kn + rb + u * 8);
      qd[u] = *(const uint4*)(Qn + rb + u * 8);
    }
    if (tid < 128) {
      vd = *(const uint4*)(C1 + vbase + (size_t)(cn * CT + (tid >> 1)) * NCATc + (tid & 1) * 8);
      gd = ((const float*)(cf + 12288))[tid];
    }
    const uint16_t* gpre = Gb + (size_t)(cn * CT) * NCATc;
    gvd.x = gpre[(size_t)(row0 + 0) * NCATc];
    gvd.y = gpre[(size_t)(row0 + 1) * NCATc];
    gvd.z = gpre[(size_t)(row0 + 2) * NCATc];
    gvd.w = gpre[(size_t)(row0 + 3) * NCATc];
  };
  auto WSTAGE = [&](const uint4 (&kd)[4], const uint4 (&qd)[4],
                    const uint4& vd, const float& gd) {
#pragma unroll
    for (int u = 0; u < 4; ++u) {
      *(uint4*)&Kb[sr * 136 + sq2 * 32 + u * 8] = kd[u];
      *(uint4*)&Qb[sr * 136 + sq2 * 32 + u * 8] = qd[u];
    }
    if (tid < 128) {
      *(uint4*)&Vb[(tid >> 1) * 24 + (tid & 1) * 8] = vd;
      gABb[tid] = gd;
    }
  };

  auto CHUNK = [&](int c, bool pre, uint4 (&kcur)[4], uint4 (&knxt)[4],
                   uint4 (&qcur)[4], uint4 (&qnxt)[4], ushort4& gvcur, ushort4& gvnxt) {
    uint4 vd; float gd = 0.f;
    if (pre) LOADS(c + 1, (c + 1) & 1, knxt, qnxt, vd, gd, gvnxt);
    const int cb = c & 1;

    // --- Phase A: P = K*S, Pq = Q*S, R = V - gA*P; hoist gB/gT ---
    f32x4 accP = {0, 0, 0, 0}, accPq = {0, 0, 0, 0};
#pragma unroll
    for (int k0 = 0; k0 < 128; k0 += 32) {
      bf16x8 ka = *(const bf16x8*)&Kb[(16 * w + lr) * 136 + k0 + lk];
      bf16x8 qa = *(const bf16x8*)&Qb[(16 * w + lr) * 136 + k0 + lk];
      bf16x8 shf = *(const bf16x8*)&Sh[lr * 136 + k0 + lk];
      bf16x8 slf = *(const bf16x8*)&Slo[lr * 136 + k0 + lk];
      accP = __builtin_amdgcn_mfma_f32_16x16x32_bf16(ka, shf, accP, 0, 0, 0);
      accP = __builtin_amdgcn_mfma_f32_16x16x32_bf16(ka, slf, accP, 0, 0, 0);
      accPq = __builtin_amdgcn_mfma_f32_16x16x32_bf16(qa, shf, accPq, 0, 0, 0);
      accPq = __builtin_amdgcn_mfma_f32_16x16x32_bf16(qa, slf, accPq, 0, 0, 0);
    }
    float gbv[4];
#pragma unroll
    for (int j = 0; j < 4; ++j) gbv[j] = gABb[64 + row0 + j];
    const float gT = gABb[127];
    {
      float rv[4];
#pragma unroll
      for (int j = 0; j < 4; ++j) {
        float vv = bf2f(Vb[(row0 + j) * 24 + vcol]);
        float ga = gABb[row0 + j];
        rv[j] = vv - ga * accP[j];
      }
      uint32_t r01 = (uint32_t)f2bf(rv[0]) | ((uint32_t)f2bf(rv[1]) << 16);
      uint32_t r23 = (uint32_t)f2bf(rv[2]) | ((uint32_t)f2bf(rv[3]) << 16);
      *(uint2*)&Rt[vcol * 72 + row0] = make_uint2(r01, r23);
    }
    sync_lds();

    // --- Phase B: O = gB*Pq + M2*R (gated store), dS = F*R, S update, WSTAGE ---
    f32x4 accO = {0, 0, 0, 0};
    f32x4 accY0 = {0, 0, 0, 0}, accY1 = {0, 0, 0, 0};
#pragma unroll
    for (int k0 = 0; k0 < 64; k0 += 32) {
      const int sw = ((((k0 >> 3) + (l >> 4)) ^ (lr & 7)) * 8);   // slot-permuted col
      bf16x8 rb8 = *(const bf16x8*)&Rt[lr * 72 + k0 + lk];
      bf16x8 ma = *(const bf16x8*)&M2b[cb][(16 * w + lr) * 64 + sw];
      bf16x8 f0 = *(const bf16x8*)&Fb[cb][(32 * w + lr) * 64 + sw];
      bf16x8 f1 = *(const bf16x8*)&Fb[cb][(32 * w + 16 + lr) * 64 + sw];
      accO = __builtin_amdgcn_mfma_f32_16x16x32_bf16(ma, rb8, accO, 0, 0, 0);
      accY0 = __builtin_amdgcn_mfma_f32_16x16x32_bf16(f0, rb8, accY0, 0, 0, 0);
      accY1 = __builtin_amdgcn_mfma_f32_16x16x32_bf16(f1, rb8, accY1, 0, 0, 0);
    }
    {
      uint16_t* gp = Gb + (size_t)(c * CT) * NCATc;
      uint16_t gvv[4] = {gvcur.x, gvcur.y, gvcur.z, gvcur.w};
#pragma unroll
      for (int j = 0; j < 4; ++j) {
        float o = gbv[j] * accPq[j] + accO[j];
        float gg = sigmoidf_(bf2f(gvv[j]));
        gp[(size_t)(row0 + j) * NCATc] = f2bf(o * gg);
      }
    }
    {
      uint16_t hi[4], lo[4];
#pragma unroll
      for (int j = 0; j < 4; ++j) {
        float s = gT * sreg[0][j] + accY0[j];
        sreg[0][j] = s;
        hi[j] = f2bf(s);
        lo[j] = f2bf(s - bf2f(hi[j]));
      }
      const int dk0 = 32 * w + (l >> 4) * 4;
      *(uint2*)&Sh[vcol * 136 + dk0] =
          make_uint2((uint32_t)hi[0] | ((uint32_t)hi[1] << 16),
                     (uint32_t)hi[2] | ((uint32_t)hi[3] << 16));
      *(uint2*)&Slo[vcol * 136 + dk0] =
          make_uint2((uint32_t)lo[0] | ((uint32_t)lo[1] << 16),
                     (uint32_t)lo[2] | ((uint32_t)lo[3] << 16));
    }
    {
      uint16_t hi[4], lo[4];
#pragma unroll
      for (int j = 0; j < 4; ++j) {
        float s = gT * sreg[1][j] + accY1[j];
        sreg[1][j] = s;
        hi[j] = f2bf(s);
        lo[j] = f2bf(s - bf2f(hi[j]));
      }
      const int dk0 = 32 * w + 16 + (l >> 4) * 4;
      *(uint2*)&Sh[vcol * 136 + dk0] =
          make_uint2((uint32_t)hi[0] | ((uint32_t)hi[1] << 16),
                     (uint32_t)hi[2] | ((uint32_t)hi[3] << 16));
      *(uint2*)&Slo[vcol * 136 + dk0] =
          make_uint2((uint32_t)lo[0] | ((uint32_t)lo[1] << 16),
                     (uint32_t)lo[2] | ((uint32_t)lo[3] << 16));
    }
    if (pre) WSTAGE(knxt, qnxt, vd, gd);
    __syncthreads();   // drains vmcnt: staged M2b/Fb[nb] ready for next chunk
  };

  // prologue: stage chunk 0 (M2/F -> buf 0), zero S
  {
    uint4 vd; float gd = 0.f;
    LOADS(0, 0, kA, qA, vd, gd, gv0);
    WSTAGE(kA, qA, vd, gd);
  }
  for (int i = tid; i < 16 * 136; i += 256) { Sh[i] = 0; Slo[i] = 0; }
  __syncthreads();

  for (int c2 = 0; c2 < NCH; c2 += 2) {
    CHUNK(c2, true, kA, kB, qA, qB, gv0, gv1);
    CHUNK(c2 + 1, c2 + 2 < NCH, kB, kA, qB, qA, gv1, gv0);
  }
}

extern "C" void kernel_launch(void* const* d_in, const int* in_sizes, int n_in,
                              void* d_out, int out_size, void* d_ws, size_t ws_size,
                              hipStream_t stream) {
  (void)in_sizes; (void)n_in; (void)out_size; (void)ws_size;
  const float* x     = (const float*)d_in[0];
  const float* wq    = (const float*)d_in[1];
  const float* wk    = (const float*)d_in[2];
  const float* wv    = (const float*)d_in[3];
  const float* wo    = (const float*)d_in[4];
  const float* qcw   = (const float*)d_in[5];
  const float* kcw   = (const float*)d_in[6];
  const float* aw    = (const float*)d_in[7];
  const float* abias = (const float*)d_in[8];
  const float* bw    = (const float*)d_in[9];
  const float* bbias = (const float*)d_in[10];
  const float* gw    = (const float*)d_in[11];
  const float* nqw   = (const float*)d_in[12];
  const float* nkw   = (const float*)d_in[13];

  // workspace layout (bytes), total ~202 MiB
  uint8_t* ws = (uint8_t*)d_ws;
  uint16_t* xb   = (uint16_t*)(ws);                 //  33,554,432  x bf16
  uint16_t* wcat = (uint16_t*)(ws + 33554432);      //  25,165,824  [wq;wk;wv;g_w] bf16
  uint16_t* wob  = (uint16_t*)(ws + 58720256);      //   8,388,608  wo bf16
  uint16_t* c1   = (uint16_t*)(ws + 67108864);      // 100,663,296  x@Wcat^T bf16 (8192x6144)
  float*    abuf = (float*)   (ws + 167772160);     //   1,048,576  alpha|beta
  uint16_t* qn   = (uint16_t*)(ws + 168820736);     //  16,777,216  normed Q bf16
  uint16_t* kn   = (uint16_t*)(ws + 185597952);     //  16,777,216  normed K bf16
  uint8_t*  cofs = (uint8_t*)ws;                    // coef 51.4MB overlays xb+wcat (dead after GEMM1)

  cast6_kernel<<<2048, 256, 0, stream>>>(x, wq, wk, wv, gw, wo, xb, wcat, wob);
  gemm256_bt<uint16_t><<<768, 512, 0, stream>>>(xb, wcat, c1, NCATc, Dc, Dc);   // QKVG
  alphabeta_kernel<<<2048, 256, 0, stream>>>(x, aw, abias, bw, bbias, abuf);
  scores_kernel<<<1024, 256, 0, stream>>>(c1, qcw, kcw, nqw, nkw, abuf, cofs, qn, kn);
  scan_kernel<<<256, 256, 0, stream>>>(qn, kn, c1, cofs);                       // gated O -> c1 G-section
  gemm256_bt<float><<<256, 512, 0, stream>>>(c1 + 4096, wob, (float*)d_out, DVc, Dc, NCATc);
}

// Round 18
// 684.118 us; speedup vs baseline: 1.0046x; 1.0046x over previous
//
#include <hip/hip_runtime.h>
#include <stdint.h>

#define DEV static __device__ __forceinline__

typedef __bf16 bf16x8 __attribute__((ext_vector_type(8)));
typedef float f32x4 __attribute__((ext_vector_type(4)));

constexpr int Bc = 2, Sc = 4096, Dc = 2048, Hc = 16, KVHc = 8, HDc = 128;
constexpr int DQKc = 1024, DVc = 2048;
constexpr int Mc = Bc * Sc;       // 8192 rows
constexpr int NCATc = 6144;       // Q(1024) | K(1024) | V(2048) | Graw(2048)
constexpr int CT = 64;            // scan chunk length
constexpr int NCH = Sc / CT;      // 64 chunks per sequence
constexpr int COEF_STRIDE = 25088; // bytes: M2 8KB | F 16KB | gA/gB 512B
constexpr float EPSc = 1e-6f;

DEV uint16_t f2bf(float f) {
  uint32_t u = __float_as_uint(f);
  u += 0x7FFFu + ((u >> 16) & 1u);   // RNE
  return (uint16_t)(u >> 16);
}
DEV float bf2f(uint16_t h) { return __uint_as_float(((uint32_t)h) << 16); }
DEV float sigmoidf_(float z) { return 1.0f / (1.0f + __expf(-z)); }

DEV void unpack8(uint4 u, float* f) {
  f[0] = __uint_as_float(u.x << 16); f[1] = __uint_as_float(u.x & 0xFFFF0000u);
  f[2] = __uint_as_float(u.y << 16); f[3] = __uint_as_float(u.y & 0xFFFF0000u);
  f[4] = __uint_as_float(u.z << 16); f[5] = __uint_as_float(u.z & 0xFFFF0000u);
  f[6] = __uint_as_float(u.w << 16); f[7] = __uint_as_float(u.w & 0xFFFF0000u);
}

DEV void gload16(void* lds, const void* g) {
  auto gp = (const __attribute__((address_space(1))) uint32_t*)(uintptr_t)g;
  auto lp = (__attribute__((address_space(3))) uint32_t*)(uint32_t)(uintptr_t)lds;
  __builtin_amdgcn_global_load_lds(gp, lp, 16, 0, 0);
}

// LDS-only barrier: make ds ops visible without draining vmcnt.
DEV void sync_lds() {
  asm volatile("s_waitcnt lgkmcnt(0)" ::: "memory");
  __builtin_amdgcn_sched_barrier(0);
  __builtin_amdgcn_s_barrier();
  __builtin_amdgcn_sched_barrier(0);
}

// ---------------- fused f32 -> bf16 cast over 6 ranges ----------------
__global__ __launch_bounds__(256) void cast6_kernel(const float* __restrict__ x,
                                                    const float* __restrict__ wq,
                                                    const float* __restrict__ wk,
                                                    const float* __restrict__ wv,
                                                    const float* __restrict__ gw,
                                                    const float* __restrict__ wo,
                                                    uint16_t* __restrict__ xb,
                                                    uint16_t* __restrict__ wcat,
                                                    uint16_t* __restrict__ wob) {
  int i = blockIdx.x * blockDim.x + threadIdx.x;
  const int stride = gridDim.x * blockDim.x;
  for (; i < 8388608; i += stride) {
    const float* src;
    uint16_t* dst;
    int off;
    if (i < 4194304)      { src = x;  dst = xb;                     off = i; }
    else if (i < 4718592) { src = wq; dst = wcat;                   off = i - 4194304; }
    else if (i < 5242880) { src = wk; dst = wcat + DQKc * Dc;       off = i - 4718592; }
    else if (i < 6291456) { src = wv; dst = wcat + 2 * DQKc * Dc;   off = i - 5242880; }
    else if (i < 7340032) { src = gw; dst = wcat + 2 * DQKc * Dc + DVc * Dc; off = i - 6291456; }
    else                  { src = wo; dst = wob;                    off = i - 7340032; }
    float4 v = *(const float4*)(src + (size_t)off * 4);
    ushort4 o;
    o.x = f2bf(v.x); o.y = f2bf(v.y); o.z = f2bf(v.z); o.w = f2bf(v.w);
    *(ushort4*)(dst + (size_t)off * 4) = o;
  }
}

// ---------------- 256x256 8-phase bf16 GEMM, C = A @ B^T ----------------
// Column-major XCD mapping (requires Ndim/256 % 8 == 0). R15 single-barrier
// schedule (verified best; double-barrier gate regressed in R16).
template <typename OutT>
__global__ __launch_bounds__(512, 2) void gemm256_bt(const uint16_t* __restrict__ A,
                                                     const uint16_t* __restrict__ Bw,
                                                     OutT* __restrict__ C, int Ndim, int Kdim,
                                                     int lda) {
  __shared__ uint16_t sT[2][2][2][8192];   // [buf][mat A/B][khalf][256 rows * 32 cols]

  const int nbn = Ndim / 256;
  const int cpx = nbn >> 3;                 // bn columns per XCD
  const int xcd = blockIdx.x & 7, lin = blockIdx.x >> 3;
  const int bn = xcd * cpx + lin % cpx;
  const int bm = lin / cpx;

  const int tid = threadIdx.x;
  const int wid = tid >> 6, lane = tid & 63;
  const int wm = wid >> 2, wn = wid & 3;
  const int lr = lane & 15;
  const int sswz8 = (((lane >> 4) ^ ((lr >> 1) & 3)) * 8);
  const int arow_base = wm * 128 + lr;
  const int brow_base = wn * 64 + lr;

  const uint16_t* Ab = A + (size_t)(bm * 256) * lda;
  const uint16_t* Bb = Bw + (size_t)(bn * 256) * Kdim;
  const int NT = Kdim >> 6;

  int srowA[2];
  int soff[2];
  const int wbase = tid & ~63;
#pragma unroll
  for (int u = 0; u < 2; ++u) {
    int L = u * 512 + tid;
    srowA[u] = L >> 2;
    soff[u] = (((L & 3) ^ ((L >> 3) & 3)) * 8);
  }

  auto STAGE = [&](int buf, int mat, int kh, int kt) {
    const uint16_t* gb = mat == 0 ? Ab : Bb;
    const int ld = mat == 0 ? lda : Kdim;
    uint16_t* rg = &sT[buf][mat][kh][0];
#pragma unroll
    for (int u = 0; u < 2; ++u) {
      const uint16_t* g = gb + (size_t)srowA[u] * ld + kt * 64 + kh * 32 + soff[u];
      gload16(rg + (u * 512 + wbase) * 8, g);
    }
  };

  f32x4 acc[8][4] = {};
  bf16x8 bfr[4];

  STAGE(0, 0, 0, 0); STAGE(0, 1, 0, 0);
  STAGE(0, 0, 1, 0); STAGE(0, 1, 1, 0);
  STAGE(1, 0, 0, 1); STAGE(1, 1, 0, 1);
  asm volatile("s_waitcnt vmcnt(4)" ::: "memory");
  __builtin_amdgcn_s_barrier();

  for (int kt = 0; kt < NT; ++kt) {
    const int buf = kt & 1;
    const uint16_t* aR0 = &sT[buf][0][0][0];
    const uint16_t* bR0 = &sT[buf][1][0][0];
    const uint16_t* aR1 = &sT[buf][0][1][0];
    const uint16_t* bR1 = &sT[buf][1][1][0];

    {
      bf16x8 af[4];
#pragma unroll
      for (int m = 0; m < 4; ++m)
        af[m] = *(const bf16x8*)&aR0[(arow_base + m * 16) * 32 + sswz8];
#pragma unroll
      for (int n = 0; n < 4; ++n)
        bfr[n] = *(const bf16x8*)&bR0[(brow_base + n * 16) * 32 + sswz8];
      if (kt + 1 < NT) STAGE(buf ^ 1, 0, 1, kt + 1);
      __builtin_amdgcn_s_setprio(1);
#pragma unroll
      for (int m = 0; m < 4; ++m)
#pragma unroll
        for (int n = 0; n < 4; ++n)
          acc[m][n] = __builtin_amdgcn_mfma_f32_16x16x32_bf16(af[m], bfr[n], acc[m][n], 0, 0, 0);
      __builtin_amdgcn_s_setprio(0);
      __builtin_amdgcn_s_barrier();
    }
    {
      bf16x8 af[4];
#pragma unroll
      for (int m = 0; m < 4; ++m)
        af[m] = *(const bf16x8*)&aR0[(arow_base + (m + 4) * 16) * 32 + sswz8];
      if (kt + 1 < NT) STAGE(buf ^ 1, 1, 1, kt + 1);
      __builtin_amdgcn_s_setprio(1);
#pragma unroll
      for (int m = 0; m < 4; ++m)
#pragma unroll
        for (int n = 0; n < 4; ++n)
          acc[m + 4][n] = __builtin_amdgcn_mfma_f32_16x16x32_bf16(af[m], bfr[n], acc[m + 4][n], 0, 0, 0);
      __builtin_amdgcn_s_setprio(0);
      __builtin_amdgcn_s_barrier();
    }
    {
      bf16x8 af[4];
#pragma unroll
      for (int m = 0; m < 4; ++m)
        af[m] = *(const bf16x8*)&aR1[(arow_base + m * 16) * 32 + sswz8];
#pragma unroll
      for (int n = 0; n < 4; ++n)
        bfr[n] = *(const bf16x8*)&bR1[(brow_base + n * 16) * 32 + sswz8];
      if (kt + 2 < NT) STAGE(buf, 0, 0, kt + 2);
      __builtin_amdgcn_s_setprio(1);
#pragma unroll
      for (int m = 0; m < 4; ++m)
#pragma unroll
        for (int n = 0; n < 4; ++n)
          acc[m][n] = __builtin_amdgcn_mfma_f32_16x16x32_bf16(af[m], bfr[n], acc[m][n], 0, 0, 0);
      __builtin_amdgcn_s_setprio(0);
      __builtin_amdgcn_s_barrier();
    }
    {
      bf16x8 af[4];
#pragma unroll
      for (int m = 0; m < 4; ++m)
        af[m] = *(const bf16x8*)&aR1[(arow_base + (m + 4) * 16) * 32 + sswz8];
      if (kt + 2 < NT) STAGE(buf, 1, 0, kt + 2);
      __builtin_amdgcn_s_setprio(1);
#pragma unroll
      for (int m = 0; m < 4; ++m)
#pragma unroll
        for (int n = 0; n < 4; ++n)
          acc[m + 4][n] = __builtin_amdgcn_mfma_f32_16x16x32_bf16(af[m], bfr[n], acc[m + 4][n], 0, 0, 0);
      __builtin_amdgcn_s_setprio(0);
    }
    if (kt + 1 < NT) {
      if (kt + 2 < NT)
        asm volatile("s_waitcnt vmcnt(4)" ::: "memory");
      else
        asm volatile("s_waitcnt vmcnt(0)" ::: "memory");
      __builtin_amdgcn_s_barrier();
    }
  }

  const int r0 = (lane >> 4) * 4;
#pragma unroll
  for (int m = 0; m < 8; ++m)
#pragma unroll
    for (int n = 0; n < 4; ++n) {
      int col = bn * 256 + wn * 64 + n * 16 + lr;
#pragma unroll
      for (int j = 0; j < 4; ++j) {
        int row = bm * 256 + wm * 128 + m * 16 + r0 + j;
        float val = acc[m][n][j];
        if constexpr (sizeof(OutT) == 2)
          C[(size_t)row * Ndim + col] = (OutT)f2bf(val);
        else
          C[(size_t)row * Ndim + col] = (OutT)val;
      }
    }
}

// ---------------- alpha/beta (fp32, sigmoid fused, 4 rows/block, 8-way K-split) ----------------
__global__ __launch_bounds__(256) void alphabeta_kernel(const float* __restrict__ x,
                                                        const float* __restrict__ aw,
                                                        const float* __restrict__ abias,
                                                        const float* __restrict__ bw,
                                                        const float* __restrict__ bbias,
                                                        float* __restrict__ out) {
  __shared__ float xs[4 * Dc];   // 32 KB
  const int row0 = blockIdx.x * 4;
  const float* xp = x + (size_t)row0 * Dc;
  for (int i = threadIdx.x; i < 4 * Dc / 4; i += 256)
    *(float4*)&xs[i * 4] = *(const float4*)(xp + (size_t)i * 4);
  __syncthreads();
  const int o = threadIdx.x >> 3, lg = threadIdx.x & 7;
  const float* wrow = (o < 16) ? (aw + (size_t)o * Dc) : (bw + (size_t)(o - 16) * Dc);
  float s0 = 0.f, s1 = 0.f, s2 = 0.f, s3 = 0.f;
  for (int k = lg * 4; k < Dc; k += 32) {
    float4 wv = *(const float4*)(wrow + k);
    float4 x0 = *(const float4*)&xs[k];
    float4 x1 = *(const float4*)&xs[Dc + k];
    float4 x2 = *(const float4*)&xs[2 * Dc + k];
    float4 x3 = *(const float4*)&xs[3 * Dc + k];
    s0 += x0.x * wv.x + x0.y * wv.y + x0.z * wv.z + x0.w * wv.w;
    s1 += x1.x * wv.x + x1.y * wv.y + x1.z * wv.z + x1.w * wv.w;
    s2 += x2.x * wv.x + x2.y * wv.y + x2.z * wv.z + x2.w * wv.w;
    s3 += x3.x * wv.x + x3.y * wv.y + x3.z * wv.z + x3.w * wv.w;
  }
#pragma unroll
  for (int m = 1; m < 8; m <<= 1) {
    s0 += __shfl_xor(s0, m); s1 += __shfl_xor(s1, m);
    s2 += __shfl_xor(s2, m); s3 += __shfl_xor(s3, m);
  }
  if (lg == 0) {
    float bias = (o < 16) ? abias[o] : bbias[o - 16];
    float scale = (o >= 16) ? 0.08838834764831845f : 1.0f;   // 1/sqrt(128)
    out[(size_t)(row0 + 0) * 32 + o] = sigmoidf_(s0 + bias) * scale;
    out[(size_t)(row0 + 1) * 32 + o] = sigmoidf_(s1 + bias) * scale;
    out[(size_t)(row0 + 2) * 32 + o] = sigmoidf_(s2 + bias) * scale;
    out[(size_t)(row0 + 3) * 32 + o] = sigmoidf_(s3 + bias) * scale;
  }
}

// ---------------- per-chunk coefficient precompute (T=64, GQA-deduped, +F) ----------------
// FUSES causal conv(k=4) + head RMSNorm: reads RAW C1 Q/K sections, computes
// normed bf16 K/Q into LDS (MFMA) AND global Qn/Kn (scan) — single rounding.
__global__ __launch_bounds__(256) void scores_kernel(const uint16_t* __restrict__ C1,
                                                     const float* __restrict__ qcw,
                                                     const float* __restrict__ kcw,
                                                     const float* __restrict__ nqw,
                                                     const float* __restrict__ nkw,
                                                     const float* __restrict__ ab,
                                                     uint8_t* __restrict__ coef,
                                                     uint16_t* __restrict__ Qn,
                                                     uint16_t* __restrict__ Kn) {
  __shared__ __align__(16) char smem[137728];
  uint16_t* sK = (uint16_t*)smem;                  // [64][136]
  uint16_t* sQ = (uint16_t*)(smem + 17408);        // [64][136]
  uint16_t* sF = (uint16_t*)smem;                  // alias after solve: [128][72]
  uint16_t* sM2 = (uint16_t*)(smem + 18432);       // alias after solve: [64][72]
  float* Lb = (float*)(smem + 108544);             // [2][64]
  float* bbv = Lb + 128;                           // [2][64]
  uint16_t* Ktg = (uint16_t*)(smem + 109568);      // [128][72] K^T (swizzled cols)
  uint16_t* Et = (uint16_t*)(smem + 128000);       // [64][72] E^T bf16 (per-head)
  float* gCb = (float*)(smem + 137216);            // [2][64]

  auto Wt_p  = [&](int hd) { return (float*)(smem + hd * 17408); };
  auto Msh_p = [&](int hd) { return (uint16_t*)(smem + 34816 + hd * 18432); };
  auto Msl_p = [&](int hd) { return (uint16_t*)(smem + 44032 + hd * 18432); };
  auto Thh_p = [&](int hd) { return (uint16_t*)(smem + 71680 + hd * 18432); };
  auto Thl_p = [&](int hd) { return (uint16_t*)(smem + 80896 + hd * 18432); };

  const int bid = blockIdx.x;
  const int c = bid & 63, kh = (bid >> 6) & 7, b = bid >> 9;
  const int t0 = c * 64;
  const int tid = threadIdx.x;
  const int w = tid >> 6, l = tid & 63, lr = l & 15, lk = (l >> 4) * 8;
  const int sr = tid >> 2, sq2 = tid & 3;

  auto cb_p = [&](int hd) {
    return coef + (size_t)((b * Hc + kh * 2 + hd) * NCH + c) * COEF_STRIDE;
  };

  {  // fused conv(k=4)+RMSNorm staging
    const int ch0 = sq2 * 32;
    const int t = t0 + sr;
    float qa[32], ka[32];
    float sqs = 0.f, sks = 0.f;
#pragma unroll
    for (int u = 0; u < 4; ++u) {
      uint4 qt[4], kt4[4];
#pragma unroll
      for (int j = 0; j < 4; ++j) {
        int tt = t - 3 + j;
        if (tt >= 0) {
          size_t rbj = (size_t)(b * Sc + tt) * NCATc + kh * HDc + ch0 + u * 8;
          qt[j] = *(const uint4*)(C1 + rbj);
          kt4[j] = *(const uint4*)(C1 + rbj + 1024);
        } else {
          qt[j] = make_uint4(0, 0, 0, 0);
          kt4[j] = make_uint4(0, 0, 0, 0);
        }
      }
      float qf[4][8], kf[4][8];
#pragma unroll
      for (int j = 0; j < 4; ++j) { unpack8(qt[j], qf[j]); unpack8(kt4[j], kf[j]); }
#pragma unroll
      for (int e = 0; e < 8; ++e) {
        const int ch = kh * HDc + ch0 + u * 8 + e;
        float4 wq4 = *(const float4*)(qcw + ch * 4);
        float4 wk4 = *(const float4*)(kcw + ch * 4);
        float qv = qf[0][e] * wq4.x + qf[1][e] * wq4.y + qf[2][e] * wq4.z + qf[3][e] * wq4.w;
        float kv = kf[0][e] * wk4.x + kf[1][e] * wk4.y + kf[2][e] * wk4.z + kf[3][e] * wk4.w;
        qa[u * 8 + e] = qv; ka[u * 8 + e] = kv;
        sqs += qv * qv; sks += kv * kv;
      }
    }
    sqs += __shfl_xor(sqs, 1); sqs += __shfl_xor(sqs, 2);
    sks += __shfl_xor(sks, 1); sks += __shfl_xor(sks, 2);
    const float rq = rsqrtf(sqs * (1.f / HDc) + EPSc);
    const float rk = rsqrtf(sks * (1.f / HDc) + EPSc);
    const size_t gq = (size_t)(b * Sc + t) * DQKc + kh * HDc + ch0;
#pragma unroll
    for (int u = 0; u < 4; ++u) {
      uint32_t qpk[4], kpk[4];
#pragma unroll
      for (int p = 0; p < 4; ++p) {
        const int e = u * 8 + p * 2;
        const int cc = ch0 + e;
        uint16_t q0 = f2bf(nqw[cc] * qa[e] * rq);
        uint16_t q1 = f2bf(nqw[cc + 1] * qa[e + 1] * rq);
        uint16_t k0 = f2bf(nkw[cc] * ka[e] * rk);
        uint16_t k1 = f2bf(nkw[cc + 1] * ka[e + 1] * rk);
        qpk[p] = (uint32_t)q0 | ((uint32_t)q1 << 16);
        kpk[p] = (uint32_t)k0 | ((uint32_t)k1 << 16);
      }
      uint4 qv4 = make_uint4(qpk[0], qpk[1], qpk[2], qpk[3]);
      uint4 kv4 = make_uint4(kpk[0], kpk[1], kpk[2], kpk[3]);
      *(uint4*)&sQ[sr * 136 + ch0 + u * 8] = qv4;
      *(uint4*)&sK[sr * 136 + ch0 + u * 8] = kv4;
      *(uint4*)(Qn + gq + u * 8) = qv4;
      *(uint4*)(Kn + gq + u * 8) = kv4;
    }
  }
  if (tid < 128) {  // log-space decays
    const int hd = tid >> 6, tt = tid & 63;
    const float* abp = ab + (size_t)(b * Sc + t0 + tt) * 32 + (kh * 2 + hd);
    float av = fmaxf(abp[0], 1e-30f);
    float bv = abp[16];
    float la = log2f(av);
    float L = la;
#pragma unroll
    for (int off = 1; off < 64; off <<= 1) {
      float up = __shfl_up(L, off, 64);
      if (tt >= off) L += up;
    }
    Lb[hd * 64 + tt] = L; bbv[hd * 64 + tt] = bv;
    float* gout = (float*)(cb_p(hd) + 24576);
    gout[tt] = exp2f(L - la);   // gA = G_{i-1}
    gout[64 + tt] = exp2f(L);   // gB = G_i
  }
  __syncthreads();

  // KK = K K^T, QK = Q K^T
  f32x4 kkacc[4] = {}, qkacc[4] = {};
#pragma unroll
  for (int k0 = 0; k0 < 128; k0 += 32) {
    bf16x8 ka = *(const bf16x8*)&sK[(16 * w + lr) * 136 + k0 + lk];
    bf16x8 qa = *(const bf16x8*)&sQ[(16 * w + lr) * 136 + k0 + lk];
#pragma unroll
    for (int n = 0; n < 4; ++n) {
      bf16x8 kb = *(const bf16x8*)&sK[(16 * n + lr) * 136 + k0 + lk];
      kkacc[n] = __builtin_amdgcn_mfma_f32_16x16x32_bf16(ka, kb, kkacc[n], 0, 0, 0);
      qkacc[n] = __builtin_amdgcn_mfma_f32_16x16x32_bf16(qa, kb, qkacc[n], 0, 0, 0);
    }
  }
  __syncthreads();

  // K^T scatter (sq2-keyed col swizzle) + per-head gC, while sK still valid
  {
#pragma unroll
    for (int u = 0; u < 4; ++u) {
      uint4 kd = *(const uint4*)&sK[sr * 136 + sq2 * 32 + u * 8];
      const int c0 = sq2 * 32 + u * 8;
      const int tsw = sr ^ (sq2 << 4);
      uint32_t x0 = kd.x, x1 = kd.y, x2 = kd.z, x3 = kd.w;
      Ktg[(c0 + 0) * 72 + tsw] = (uint16_t)x0; Ktg[(c0 + 1) * 72 + tsw] = (uint16_t)(x0 >> 16);
      Ktg[(c0 + 2) * 72 + tsw] = (uint16_t)x1; Ktg[(c0 + 3) * 72 + tsw] = (uint16_t)(x1 >> 16);
      Ktg[(c0 + 4) * 72 + tsw] = (uint16_t)x2; Ktg[(c0 + 5) * 72 + tsw] = (uint16_t)(x2 >> 16);
      Ktg[(c0 + 6) * 72 + tsw] = (uint16_t)x3; Ktg[(c0 + 7) * 72 + tsw] = (uint16_t)(x3 >> 16);
    }
    if (tid < 128) {
      const int hd = tid >> 6, tt = tid & 63;
      gCb[hd * 64 + tt] = exp2f(Lb[hd * 64 + 63] - Lb[hd * 64 + tt]) * bbv[hd * 64 + tt];
    }
  }
  __syncthreads();

  // fold per head (overwrites sK/sQ with Wt0/Wt1)
#pragma unroll
  for (int hd = 0; hd < 2; ++hd) {
    float* Wt = Wt_p(hd);
    uint16_t* Mh = Msh_p(hd);
    uint16_t* Ml = Msl_p(hd);
    const float* Lh = Lb + hd * 64;
    const float* bh = bbv + hd * 64;
#pragma unroll
    for (int n = 0; n < 4; ++n)
#pragma unroll
      for (int jj = 0; jj < 4; ++jj) {
        const int i = 16 * w + (l >> 4) * 4 + jj;
        const int j = 16 * n + lr;
        float Li = Lh[i];
        float Lim = (i > 0) ? Lh[(i > 0) ? i - 1 : 0] : 0.f;
        float Lj = Lh[j];
        float bj = bh[j];
        float wv = (j < i) ? exp2f(Lim - Lj) * bj * kkacc[n][jj] : 0.f;
        Wt[j * 68 + i] = wv;                       // W^T
        float ms = (j <= i) ? exp2f(Li - Lj) * bj * qkacc[n][jj] : 0.f;
        uint16_t mh = f2bf(ms);
        Mh[i * 72 + j] = mh;
        Ml[i * 72 + j] = f2bf(ms - bf2f(mh));
      }
  }
  __syncthreads();

  // Tinv = (I + tril(W,-1))^-1 forward substitution; wave hd solves head hd.
  if (tid < 128) {
    const int hd = tid >> 6, col = tid & 63;
    float* Wt = Wt_p(hd);
    uint16_t* Th = Thh_p(hd);
    uint16_t* Tl = Thl_p(hd);
    float acc[64];
#pragma unroll
    for (int i = 0; i < 64; ++i) acc[i] = 0.f;
#pragma unroll
    for (int ll = 0; ll < 64; ++ll) {
      float xl = ((col == ll) ? 1.f : 0.f) - acc[ll];
      uint16_t xh = f2bf(xl);
      Th[col * 72 + ll] = xh;                      // transposed: [col j][row l]
      Tl[col * 72 + ll] = f2bf(xl - bf2f(xh));
#pragma unroll
      for (int i = ll + 1; i < 64; ++i)
        acc[i] = fmaf(Wt[ll * 68 + i], xl, acc[i]);
    }
  }
  __syncthreads();

  for (int hd = 0; hd < 2; ++hd) {
    uint16_t* Mh = Msh_p(hd);
    uint16_t* Ml = Msl_p(hd);
    uint16_t* Th = Thh_p(hd);
    uint16_t* Tl = Thl_p(hd);
    uint16_t* m2out = (uint16_t*)cb_p(hd);
    uint16_t* fout = (uint16_t*)cb_p(hd) + 4096;

    // a) Et^T[j][t] = gC[t]*(Thh+Thl)[j][t]
    {
      const int j2 = tid >> 2, tq = tid & 3;
#pragma unroll
      for (int p = 0; p < 16; ++p) {
        int t1 = tq * 16 + p;
        float ev = gCb[hd * 64 + t1] * (bf2f(Th[j2 * 72 + t1]) + bf2f(Tl[j2 * 72 + t1]));
        Et[j2 * 72 + t1] = f2bf(ev);
      }
    }
    __syncthreads();

    // b) M2 = M_s * Tinv (hi/lo MFMA); F = K^T * E (MFMA)
    f32x4 m2acc[4] = {};
#pragma unroll
    for (int k0 = 0; k0 < 64; k0 += 32) {
      bf16x8 ah = *(const bf16x8*)&Mh[(16 * w + lr) * 72 + k0 + lk];
      bf16x8 al = *(const bf16x8*)&Ml[(16 * w + lr) * 72 + k0 + lk];
#pragma unroll
      for (int n = 0; n < 4; ++n) {
        bf16x8 bhf = *(const bf16x8*)&Th[(16 * n + lr) * 72 + k0 + lk];
        bf16x8 blf = *(const bf16x8*)&Tl[(16 * n + lr) * 72 + k0 + lk];
        m2acc[n] = __builtin_amdgcn_mfma_f32_16x16x32_bf16(ah, bhf, m2acc[n], 0, 0, 0);
        m2acc[n] = __builtin_amdgcn_mfma_f32_16x16x32_bf16(ah, blf, m2acc[n], 0, 0, 0);
        m2acc[n] = __builtin_amdgcn_mfma_f32_16x16x32_bf16(al, bhf, m2acc[n], 0, 0, 0);
      }
    }
    f32x4 facc[2][4] = {};
#pragma unroll
    for (int k0 = 0; k0 < 64; k0 += 32) {
      bf16x8 eb[4];
#pragma unroll
      for (int n = 0; n < 4; ++n)
        eb[n] = *(const bf16x8*)&Et[(16 * n + lr) * 72 + k0 + lk];
      const int ksw = (k0 + lk) ^ (w << 4);
      bf16x8 ka0 = *(const bf16x8*)&Ktg[(32 * w + lr) * 72 + ksw];
      bf16x8 ka1 = *(const bf16x8*)&Ktg[(32 * w + 16 + lr) * 72 + ksw];
#pragma unroll
      for (int n = 0; n < 4; ++n) {
        facc[0][n] = __builtin_amdgcn_mfma_f32_16x16x32_bf16(ka0, eb[n], facc[0][n], 0, 0, 0);
        facc[1][n] = __builtin_amdgcn_mfma_f32_16x16x32_bf16(ka1, eb[n], facc[1][n], 0, 0, 0);
      }
    }
#pragma unroll
    for (int n = 0; n < 4; ++n)
#pragma unroll
      for (int jj = 0; jj < 4; ++jj) {
        const int i = 16 * w + (l >> 4) * 4 + jj;
        const int j = 16 * n + lr;
        sM2[i * 72 + j] = f2bf(m2acc[n][jj]);
        sF[(32 * w + (l >> 4) * 4 + jj) * 72 + j] = f2bf(facc[0][n][jj]);
        sF[(32 * w + 16 + (l >> 4) * 4 + jj) * 72 + j] = f2bf(facc[1][n][jj]);
      }
    __syncthreads();
    // c) packed copies out, slot-permuted: logical slot s of row r -> s ^ (r&7)
    {
      const int i2 = tid >> 2, tq = tid & 3;
      uint4 a0 = *(const uint4*)&sM2[i2 * 72 + tq * 16];
      uint4 a1 = *(const uint4*)&sM2[i2 * 72 + tq * 16 + 8];
      *(uint4*)(m2out + i2 * 64 + ((2 * tq) ^ (i2 & 7)) * 8) = a0;
      *(uint4*)(m2out + i2 * 64 + ((2 * tq + 1) ^ (i2 & 7)) * 8) = a1;
#pragma unroll
      for (int e = 0; e < 4; ++e) {
        int L = tid * 4 + e;
        int rw = L >> 3, s = L & 7;
        *(uint4*)(fout + rw * 64 + (s ^ (rw & 7)) * 8) = *(const uint4*)&sF[rw * 72 + s * 8];
      }
    }
    __syncthreads();   // protect sM2/sF/Et before next head
  }
}

// ---------------- MFMA chunked gated delta-rule scan (T=64, 2-phase) ----------------
__global__ __launch_bounds__(256, 1) void scan_kernel(const uint16_t* __restrict__ Qn,
                                                      const uint16_t* __restrict__ Kn,
                                                      uint16_t* C1,
                                                      const uint8_t* __restrict__ coef) {
  __shared__ __align__(16) uint16_t Kb[64 * 136];
  __shared__ __align__(16) uint16_t Qb[64 * 136];
  __shared__ __align__(16) uint16_t M2b[2][64 * 64];   // linear, slot-permuted
  __shared__ __align__(16) uint16_t Fb[2][128 * 64];   // linear, slot-permuted
  __shared__ __align__(16) uint16_t Vb[64 * 24];
  __shared__ __align__(16) uint16_t Rt[16 * 72];     // R^T [v][t]
  __shared__ __align__(16) uint16_t Sh[16 * 136];    // S^T hi [v][dk]
  __shared__ __align__(16) uint16_t Slo[16 * 136];   // S^T lo [v][dk]
  __shared__ float gABb[128];                        // gA[64] | gB[64]

  const int bid = blockIdx.x;
  const int kh = bid & 7;
  const int j2 = bid >> 3;
  const int sl = j2 >> 2;
  const int b = (j2 >> 1) & 1;
  const int h = kh * 2 + (j2 & 1);
  const int ch0 = (b * Hc + h) * NCH;

  const int tid = threadIdx.x;
  const int w = tid >> 6, l = tid & 63;
  const int lr = l & 15, lk = (l >> 4) * 8;
  const int row0 = 16 * w + (l >> 4) * 4;
  const int vcol = lr;
  const int sr = tid >> 2, sq2 = tid & 3;
  const int wbase = tid & ~63;

  const size_t kqbase = (size_t)(b * Sc) * DQKc + kh * HDc;
  const size_t vbase = (size_t)(b * Sc) * NCATc + 2048 + h * HDc + sl * 16;
  uint16_t* Gb = C1 + (size_t)(b * Sc) * NCATc + 4096 + h * HDc + sl * 16 + vcol;

  float sreg[2][4] = {};
  uint4 kA[4], kB[4], qA[4], qB[4];
  ushort4 gv0, gv1;

  auto LOADS = [&](int cn, int nb, uint4 (&kd)[4], uint4 (&qd)[4],
                   uint4& vd, float& gd, ushort4& gvd) {
    const uint16_t* cf = (const uint16_t*)(coef + (size_t)(ch0 + cn) * COEF_STRIDE);
#pragma unroll
    for (int u = 0; u < 2; ++u)
      gload16(&M2b[nb][(u * 256 + wbase) * 8], cf + (size_t)(u * 256 + tid) * 8);
#pragma unroll
    for (int u = 0; u < 4; ++u)
      gload16(&Fb[nb][(u * 256 + wbase) * 8], cf + 4096 + (size_t)(u * 256 + tid) * 8);
    const size_t rb = kqbase + (size_t)(cn * CT + sr) * DQKc + sq2 * 32;
#pragma unroll
    for (int u = 0; u < 4; ++u) {
      kd[u] = *(const uint4*)(Kn + rb + u * 8);
      qd[u] = *(const uint4*)(Qn + rb + u * 8);
    }
    if (tid < 128) {
      vd = *(const uint4*)(C1 + vbase + (size_t)(cn * CT + (tid >> 1)) * NCATc + (tid & 1) * 8);
      gd = ((const float*)(cf + 12288))[tid];
    }
    const uint16_t* gpre = Gb + (size_t)(cn * CT) * NCATc;
    gvd.x = gpre[(size_t)(row0 + 0) * NCATc];
    gvd.y = gpre[(size_t)(row0 + 1) * NCATc];
    gvd.z = gpre[(size_t)(row0 + 2) * NCATc];
    gvd.w = gpre[(size_t)(row0 + 3) * NCATc];
  };
  auto WSTAGE = [&](const uint4 (&kd)[4], const uint4 (&qd)[4],
                    const uint4& vd, const float& gd) {
#pragma unroll
    for (int u = 0; u < 4; ++u) {
      *(uint4*)&Kb[sr * 136 + sq2 * 32 + u * 8] = kd[u];
      *(uint4*)&Qb[sr * 136 + sq2 * 32 + u * 8] = qd[u];
    }
    if (tid < 128) {
      *(uint4*)&Vb[(tid >> 1) * 24 + (tid & 1) * 8] = vd;
      gABb[tid] = gd;
    }
  };

  auto CHUNK = [&](int c, bool pre, uint4 (&kcur)[4], uint4 (&knxt)[4],
                   uint4 (&qcur)[4], uint4 (&qnxt)[4], ushort4& gvcur, ushort4& gvnxt) {
    uint4 vd; float gd = 0.f;
    if (pre) LOADS(c + 1, (c + 1) & 1, knxt, qnxt, vd, gd, gvnxt);
    const int cb = c & 1;

    // --- Phase A: P = K*S, Pq = Q*S, R = V - gA*P; hoist gB/gT ---
    f32x4 accP = {0, 0, 0, 0}, accPq = {0, 0, 0, 0};
#pragma unroll
    for (int k0 = 0; k0 < 128; k0 += 32) {
      bf16x8 ka = *(const bf16x8*)&Kb[(16 * w + lr) * 136 + k0 + lk];
      bf16x8 qa = *(const bf16x8*)&Qb[(16 * w + lr) * 136 + k0 + lk];
      bf16x8 shf = *(const bf16x8*)&Sh[lr * 136 + k0 + lk];
      bf16x8 slf = *(const bf16x8*)&Slo[lr * 136 + k0 + lk];
      accP = __builtin_amdgcn_mfma_f32_16x16x32_bf16(ka, shf, accP, 0, 0, 0);
      accP = __builtin_amdgcn_mfma_f32_16x16x32_bf16(ka, slf, accP, 0, 0, 0);
      accPq = __builtin_amdgcn_mfma_f32_16x16x32_bf16(qa, shf, accPq, 0, 0, 0);
      accPq = __builtin_amdgcn_mfma_f32_16x16x32_bf16(qa, slf, accPq, 0, 0, 0);
    }
    float gbv[4];
#pragma unroll
    for (int j = 0; j < 4; ++j) gbv[j] = gABb[64 + row0 + j];
    const float gT = gABb[127];
    {
      float rv[4];
#pragma unroll
      for (int j = 0; j < 4; ++j) {
        float vv = bf2f(Vb[(row0 + j) * 24 + vcol]);
        float ga = gABb[row0 + j];
        rv[j] = vv - ga * accP[j];
      }
      uint32_t r01 = (uint32_t)f2bf(rv[0]) | ((uint32_t)f2bf(rv[1]) << 16);
      uint32_t r23 = (uint32_t)f2bf(rv[2]) | ((uint32_t)f2bf(rv[3]) << 16);
      *(uint2*)&Rt[vcol * 72 + row0] = make_uint2(r01, r23);
    }
    sync_lds();

    // --- Phase B: O = gB*Pq + M2*R (gated store), dS = F*R, S update, WSTAGE ---
    f32x4 accO = {0, 0, 0, 0};
    f32x4 accY0 = {0, 0, 0, 0}, accY1 = {0, 0, 0, 0};
#pragma unroll
    for (int k0 = 0; k0 < 64; k0 += 32) {
      const int sw = ((((k0 >> 3) + (l >> 4)) ^ (lr & 7)) * 8);   // slot-permuted col
      bf16x8 rb8 = *(const bf16x8*)&Rt[lr * 72 + k0 + lk];
      bf16x8 ma = *(const bf16x8*)&M2b[cb][(16 * w + lr) * 64 + sw];
      bf16x8 f0 = *(const bf16x8*)&Fb[cb][(32 * w + lr) * 64 + sw];
      bf16x8 f1 = *(const bf16x8*)&Fb[cb][(32 * w + 16 + lr) * 64 + sw];
      accO = __builtin_amdgcn_mfma_f32_16x16x32_bf16(ma, rb8, accO, 0, 0, 0);
      accY0 = __builtin_amdgcn_mfma_f32_16x16x32_bf16(f0, rb8, accY0, 0, 0, 0);
      accY1 = __builtin_amdgcn_mfma_f32_16x16x32_bf16(f1, rb8, accY1, 0, 0, 0);
    }
    {
      uint16_t* gp = Gb + (size_t)(c * CT) * NCATc;
      uint16_t gvv[4] = {gvcur.x, gvcur.y, gvcur.z, gvcur.w};
#pragma unroll
      for (int j = 0; j < 4; ++j) {
        float o = gbv[j] * accPq[j] + accO[j];
        float gg = sigmoidf_(bf2f(gvv[j]));
        gp[(size_t)(row0 + j) * NCATc] = f2bf(o * gg);
      }
    }
    {
      uint16_t hi[4], lo[4];
#pragma unroll
      for (int j = 0; j < 4; ++j) {
        float s = gT * sreg[0][j] + accY0[j];
        sreg[0][j] = s;
        hi[j] = f2bf(s);
        lo[j] = f2bf(s - bf2f(hi[j]));
      }
      const int dk0 = 32 * w + (l >> 4) * 4;
      *(uint2*)&Sh[vcol * 136 + dk0] =
          make_uint2((uint32_t)hi[0] | ((uint32_t)hi[1] << 16),
                     (uint32_t)hi[2] | ((uint32_t)hi[3] << 16));
      *(uint2*)&Slo[vcol * 136 + dk0] =
          make_uint2((uint32_t)lo[0] | ((uint32_t)lo[1] << 16),
                     (uint32_t)lo[2] | ((uint32_t)lo[3] << 16));
    }
    {
      uint16_t hi[4], lo[4];
#pragma unroll
      for (int j = 0; j < 4; ++j) {
        float s = gT * sreg[1][j] + accY1[j];
        sreg[1][j] = s;
        hi[j] = f2bf(s);
        lo[j] = f2bf(s - bf2f(hi[j]));
      }
      const int dk0 = 32 * w + 16 + (l >> 4) * 4;
      *(uint2*)&Sh[vcol * 136 + dk0] =
          make_uint2((uint32_t)hi[0] | ((uint32_t)hi[1] << 16),
                     (uint32_t)hi[2] | ((uint32_t)hi[3] << 16));
      *(uint2*)&Slo[vcol * 136 + dk0] =
          make_uint2((uint32_t)lo[0] | ((uint32_t)lo[1] << 16),
                     (uint32_t)lo[2] | ((uint32_t)lo[3] << 16));
    }
    if (pre) WSTAGE(knxt, qnxt, vd, gd);
    __syncthreads();   // drains vmcnt: staged M2b/Fb[nb] ready for next chunk
  };

  // prologue: stage chunk 0 (M2/F -> buf 0), zero S
  {
    uint4 vd; float gd = 0.f;
    LOADS(0, 0, kA, qA, vd, gd, gv0);
    WSTAGE(kA, qA, vd, gd);
  }
  for (int i = tid; i < 16 * 136; i += 256) { Sh[i] = 0; Slo[i] = 0; }
  __syncthreads();

  for (int c2 = 0; c2 < NCH; c2 += 2) {
    CHUNK(c2, true, kA, kB, qA, qB, gv0, gv1);
    CHUNK(c2 + 1, c2 + 2 < NCH, kB, kA, qB, qA, gv1, gv0);
  }
}

extern "C" void kernel_launch(void* const* d_in, const int* in_sizes, int n_in,
                              void* d_out, int out_size, void* d_ws, size_t ws_size,
                              hipStream_t stream) {
  (void)in_sizes; (void)n_in; (void)out_size; (void)ws_size;
  const float* x     = (const float*)d_in[0];
  const float* wq    = (const float*)d_in[1];
  const float* wk    = (const float*)d_in[2];
  const float* wv    = (const float*)d_in[3];
  const float* wo    = (const float*)d_in[4];
  const float* qcw   = (const float*)d_in[5];
  const float* kcw   = (const float*)d_in[6];
  const float* aw    = (const float*)d_in[7];
  const float* abias = (const float*)d_in[8];
  const float* bw    = (const float*)d_in[9];
  const float* bbias = (const float*)d_in[10];
  const float* gw    = (const float*)d_in[11];
  const float* nqw   = (const float*)d_in[12];
  const float* nkw   = (const float*)d_in[13];

  // workspace layout (bytes), total ~202 MiB
  uint8_t* ws = (uint8_t*)d_ws;
  uint16_t* xb   = (uint16_t*)(ws);                 //  33,554,432  x bf16
  uint16_t* wcat = (uint16_t*)(ws + 33554432);      //  25,165,824  [wq;wk;wv;g_w] bf16
  uint16_t* wob  = (uint16_t*)(ws + 58720256);      //   8,388,608  wo bf16
  uint16_t* c1   = (uint16_t*)(ws + 67108864);      // 100,663,296  x@Wcat^T bf16 (8192x6144)
  float*    abuf = (float*)   (ws + 167772160);     //   1,048,576  alpha|beta
  uint16_t* qn   = (uint16_t*)(ws + 168820736);     //  16,777,216  normed Q bf16
  uint16_t* kn   = (uint16_t*)(ws + 185597952);     //  16,777,216  normed K bf16
  uint8_t*  cofs = (uint8_t*)ws;                    // coef 51.4MB overlays xb+wcat (dead after GEMM1)

  cast6_kernel<<<2048, 256, 0, stream>>>(x, wq, wk, wv, gw, wo, xb, wcat, wob);
  gemm256_bt<uint16_t><<<768, 512, 0, stream>>>(xb, wcat, c1, NCATc, Dc, Dc);   // QKVG
  alphabeta_kernel<<<2048, 256, 0, stream>>>(x, aw, abias, bw, bbias, abuf);
  scores_kernel<<<1024, 256, 0, stream>>>(c1, qcw, kcw, nqw, nkw, abuf, cofs, qn, kn);
  scan_kernel<<<256, 256, 0, stream>>>(qn, kn, c1, cofs);                       // gated O -> c1 G-section
  gemm256_bt<float><<<256, 512, 0, stream>>>(c1 + 4096, wob, (float*)d_out, DVc, Dc, NCATc);
}